// Round 11
// baseline (58.159 us; speedup 1.0000x reference)
//
#include <hip/hip_runtime.h>
#include <utility>
#include <type_traits>

typedef float f2 __attribute__((ext_vector_type(2)));

// ================= compile-time math (mirrors reference) =================
constexpr int cabs_i(int x){ return x < 0 ? -x : x; }
constexpr int cmax_i(int a, int b){ return a > b ? a : b; }
constexpr int cmin_i(int a, int b){ return a < b ? a : b; }
constexpr double cfact(int n){ double r = 1.0; for (int i = 2; i <= n; ++i) r *= (double)i; return r; }
constexpr double csqrt_d(double x){
  if (x <= 0.0) return 0.0;
  double r = x > 1.0 ? x : 1.0;
  for (int i = 0; i < 64; ++i) r = 0.5 * (r + x / r);
  return r;
}
constexpr double cg_coef(int j1,int j2,int m1,int m2,int j,int m){
  if (m1 + m2 != m || j < cabs_i(j1 - j2) || j > j1 + j2) return 0.0;
  if (cabs_i(m1) > j1 || cabs_i(m2) > j2 || cabs_i(m) > j) return 0.0;
  double pref = csqrt_d((2.0*j + 1.0) * cfact(j1+j2-j) * cfact(j+j1-j2) * cfact(j+j2-j1) / cfact(j1+j2+j+1));
  pref *= csqrt_d(cfact(j+m)*cfact(j-m)*cfact(j1-m1)*cfact(j1+m1)*cfact(j2-m2)*cfact(j2+m2));
  double s = 0.0;
  const int k0 = cmax_i(0, cmax_i(j2-j-m1, j1+m2-j));
  const int k1 = cmin_i(j1+j2-j, cmin_i(j1-m1, j2+m2));
  for (int k = k0; k <= k1; ++k){
    double t = 1.0/(cfact(k)*cfact(j1+j2-j-k)*cfact(j1-m1-k)*cfact(j2+m2-k)*cfact(j-j2+m1+k)*cfact(j-j1-m2+k));
    s += (k & 1) ? -t : t;
  }
  return pref * s;
}
constexpr double wd_coef(int j,int m1,int m2,int s){
  double pref = csqrt_d(cfact(j+m1)*cfact(j-m1)*cfact(j+m2)*cfact(j-m2));
  double c = pref / (cfact(j+m2-s)*cfact(s)*cfact(m1-m2+s)*cfact(j-m1-s));
  return ((m1-m2+s) & 1) ? -c : c;
}
constexpr double cgetp(double M0,double M1,double M2){
  double s = M1+M2, d = M1-M2;
  double p = (M0-s)*(M0+s)*(M0-d)*(M0+d);
  double pp = 0.5*(p + (p < 0 ? -p : p));
  return csqrt_d(pp)/(2.0*M0);
}

// ================= static_for =================
template<int Start, class F, int... Is>
__device__ inline void static_for_impl(F&& f, std::integer_sequence<int, Is...>){
  (f(std::integral_constant<int, Start + Is>{}), ...);
}
template<int Start, int End, class F>   // [Start, End)
__device__ inline void static_for(F&& f){
  if constexpr (End > Start)
    static_for_impl<Start>(static_cast<F&&>(f), std::make_integer_sequence<int, End - Start>{});
}

// ================= packed complex (re,im in one f2 -> v_pk_* ops) =======
__device__ inline f2 vfma2(f2 a, f2 b, f2 c){ return __builtin_elementwise_fma(a, b, c); }

struct cplx { f2 v; };   // v.x = re, v.y = im
__device__ inline cplx operator+(cplx a, cplx b){ return { a.v + b.v }; }
__device__ inline cplx operator*(cplx a, cplx b){
  f2 sw  = { -a.v.y, a.v.x };
  f2 bre = {  b.v.x, b.v.x };
  f2 bim = {  b.v.y, b.v.y };
  return { vfma2(a.v, bre, sw * bim) };   // 2 packed ops
}
__device__ inline cplx cconj(cplx a){ return { f2{ a.v.x, -a.v.y } }; }
__device__ inline cplx cscale(cplx x, float r){ return { x.v * f2{r, r} }; }  // 1 pk_mul
__device__ inline void caxpy(cplx& acc, float r, cplx x){   // 1 packed fma
  acc.v = vfma2(f2{r, r}, x.v, acc.v);
}

template<int n> __device__ inline float spow(float x){
  if constexpr (n <= 0) return 1.f;
  else return x * spow<n-1>(x);
}
template<int n> __device__ inline f2 vpow(f2 x){
  if constexpr (n <= 0) return f2{1.f, 1.f};
  else return x * vpow<n-1>(x);
}

// ================= wigner d in (u, v, hp) basis =========================
// u=(1+c)/2=ch^2, v=(1-c)/2=sh^2, hp=sqrt(uv)=ch*sh  (theta in [0,pi] -> hp>=0)
struct angs { float u, v, hp; };
__device__ inline angs mkang1(float c){
  angs A;
  A.u = (1.f + c) * 0.5f;
  A.v = (1.f - c) * 0.5f;
  A.hp = __builtin_amdgcn_sqrtf(A.u * A.v);
  return A;
}
struct angp { f2 u, v, hp; };   // packed over TWO DIFFERENT ANGLES
__device__ inline angp mkang2(f2 c){
  angp A;
  A.u = (c + 1.f) * 0.5f;
  A.v = (1.f - c) * 0.5f;
  f2 p = A.u * A.v;
  A.hp = f2{ __builtin_amdgcn_sqrtf(p.x), __builtin_amdgcn_sqrtf(p.y) };
  return A;
}
template<int j, int m1, int m2>
__device__ inline float wigs(const angs& A){
  constexpr int s0 = cmax_i(0, m2 - m1);
  constexpr int s1 = cmin_i(j - m1, j + m2);
  float out = 0.f;
  static_for<s0, s1 + 1>([&](auto S){
    constexpr int s = decltype(S)::value;
    constexpr float coef = (float)wd_coef(j, m1, m2, s);
    constexpr int P = 2*j + m2 - m1 - 2*s;
    constexpr int Q = m1 - m2 + 2*s;
    float mono;
    if constexpr (P & 1) mono = A.hp * spow<(P-1)/2>(A.u) * spow<(Q-1)/2>(A.v);
    else                 mono = spow<P/2>(A.u) * spow<Q/2>(A.v);
    out = fmaf(coef, mono, out);
  });
  return out;
}
template<int j, int m1, int m2>
__device__ inline f2 wig(const angp& A){
  constexpr int s0 = cmax_i(0, m2 - m1);
  constexpr int s1 = cmin_i(j - m1, j + m2);
  f2 out = {0.f, 0.f};
  static_for<s0, s1 + 1>([&](auto S){
    constexpr int s = decltype(S)::value;
    constexpr float coef = (float)wd_coef(j, m1, m2, s);
    constexpr int P = 2*j + m2 - m1 - 2*s;
    constexpr int Q = m1 - m2 + 2*s;
    f2 mono;
    if constexpr (P & 1) mono = A.hp * vpow<(P-1)/2>(A.u) * vpow<(Q-1)/2>(A.v);
    else                 mono = vpow<P/2>(A.u) * vpow<Q/2>(A.v);
    out = vfma2(f2{coef, coef}, mono, out);
  });
  return out;
}

// ================= static LS layout (from reference _build_layout) =====
struct LS { int l, s; };
template<int E> struct Entry;
template<> struct Entry<0>{ static constexpr int off = 0;  static constexpr int n = 2; static constexpr LS ls[2] = {{0,1},{2,1}}; };
template<> struct Entry<1>{ static constexpr int off = 2;  static constexpr int n = 3; static constexpr LS ls[3] = {{0,1},{2,1},{2,2}}; };
template<> struct Entry<2>{ static constexpr int off = 5;  static constexpr int n = 5; static constexpr LS ls[5] = {{0,1},{2,1},{2,2},{2,3},{4,3}}; };
template<> struct Entry<3>{ static constexpr int off = 10; static constexpr int n = 1; static constexpr LS ls[1] = {{2,1}}; };
template<> struct Entry<4>{ static constexpr int off = 11; static constexpr int n = 3; static constexpr LS ls[3] = {{0,1},{2,1},{2,2}}; };
template<> struct Entry<5>{ static constexpr int off = 14; static constexpr int n = 2; static constexpr LS ls[2] = {{0,1},{2,1}}; };

template<int E,int ja,int jb,int jc,int lb,int lc>
constexpr double hcoef(int idx){
  return cg_coef(jb, jc, lb, -lc, Entry<E>::ls[idx].s, lb - lc)
       * cg_coef(Entry<E>::ls[idx].l, Entry<E>::ls[idx].s, 0, lb - lc, ja, lb - lc);
}
template<int E,int ja,int jb,int jc,int lb,int lc>
constexpr bool hnz(){
  bool any = false;
  for (int i = 0; i < Entry<E>::n; ++i) if (hcoef<E,ja,jb,jc,lb,lc>(i) != 0.0) any = true;
  return any;
}
template<int E,int ja,int jb,int jc,int lb,int lc>
__device__ inline cplx H_ls(const cplx* par){
  cplx tot{ f2{0.f, 0.f} };
  static_for<0, Entry<E>::n>([&](auto I){
    constexpr double c = hcoef<E,ja,jb,jc,lb,lc>(decltype(I)::value);
    if constexpr (c != 0.0){
      caxpy(tot, (float)c, par[Entry<E>::off + decltype(I)::value]);
    }
  });
  return tot;
}

// ================= H table layout in d_ws =================
constexpr int IH10(int lDB){ return lDB+1; }                       // 0..2
constexpr int IH20(int lD,int lB){ return 3+(lD+1)*3+(lB+1); }     // 3..11
constexpr int IH11(int lBC,int lD){ return 12+(lBC+2)*3+(lD+1); }  // 12..26
constexpr int IH21(int lB2){ return 27+(lB2+1)/2; }                // 27..28
constexpr int IH12(int lCD,int lB){ return 29+(lCD+1)*3+(lB+1); }  // 29..37
constexpr int IH22(int lC2){ return 38+(lC2+1); }                  // 38..40
constexpr int NH = 41;

__device__ inline void compute_htab(const float2* __restrict__ g_par, cplx* t){
  cplx par[16];
  #pragma unroll
  for (int k = 0; k < 16; ++k){ float2 p = g_par[k]; par[k].v = f2{p.x, p.y}; }
  static_for<-1,2>([&](auto L){ constexpr int l = decltype(L)::value; t[IH10(l)] = H_ls<0,1,1,0,l,0>(par); });
  static_for<-1,2>([&](auto D){ constexpr int lD = decltype(D)::value;
    static_for<-1,2>([&](auto B){ constexpr int lB = decltype(B)::value;
      t[IH20(lD,lB)] = H_ls<1,1,1,1,lD,lB>(par); }); });
  static_for<-2,3>([&](auto C){ constexpr int lBC = decltype(C)::value;
    static_for<-1,2>([&](auto D){ constexpr int lD = decltype(D)::value;
      t[IH11(lBC,lD)] = H_ls<2,1,2,1,lBC,lD>(par); }); });
  t[IH21(-1)] = H_ls<3,2,1,0,-1,0>(par);
  t[IH21( 1)] = H_ls<3,2,1,0, 1,0>(par);
  static_for<-1,2>([&](auto C){ constexpr int lCD = decltype(C)::value;
    static_for<-1,2>([&](auto B){ constexpr int lB = decltype(B)::value;
      t[IH12(lCD,lB)] = H_ls<4,1,1,1,lCD,lB>(par); }); });
  static_for<-1,2>([&](auto C){ constexpr int lC2 = decltype(C)::value;
    t[IH22(lC2)] = H_ls<5,1,0,1,0,lC2>(par); });
}

template<int IDX, bool PRE>
__device__ inline cplx getH(const float2* __restrict__ hs, const cplx* ht){
  if constexpr (PRE){ float2 v = hs[IDX]; return cplx{ f2{v.x, v.y} }; }
  else return ht[IDX];
}
#define GH(IDX) getH<(IDX), PRE>(hs, ht)

// ================= physics constants =================
constexpr double dM0B = 2.01026, dM0C = 0.13957061, dM0D = 2.00685;
constexpr double dR0m0 = 4.026,  dR0g0 = 0.025;    // BD chain, J=1
constexpr double dR1m0 = 2.4607, dR1g0 = 0.0475;   // BC chain, J=2
constexpr double dR2m0 = 2.4232, dR2g0 = 0.025;    // CD chain, J=1

constexpr float M0SQ0 = (float)(dR0m0*dR0m0);
constexpr float M0SQ1 = (float)(dR1m0*dR1m0);
constexpr float M0SQ2 = (float)(dR2m0*dR2m0);
constexpr float S2_0 = (float)((dM0B+dM0D)*(dM0B+dM0D)), D2_0 = (float)((dM0B-dM0D)*(dM0B-dM0D));
constexpr float S2_1 = (float)((dM0B+dM0C)*(dM0B+dM0C)), D2_1 = (float)((dM0B-dM0C)*(dM0B-dM0C));
constexpr float S2_2 = (float)((dM0C+dM0D)*(dM0C+dM0D)), D2_2 = (float)((dM0C-dM0D)*(dM0C-dM0D));
constexpr float K0 = (float)(2.0 * cgetp(dR0m0, dM0B, dM0D) / (dR0g0 * dR0m0 * dR0m0));
constexpr float K1 = (float)(2.0 * cgetp(dR1m0, dM0B, dM0C) / (dR1g0 * dR1m0 * dR1m0));
constexpr float K2 = (float)(2.0 * cgetp(dR2m0, dM0C, dM0D) / (dR2g0 * dR2m0 * dR2m0));

__device__ inline void bw_eval2(f2 m, f2 K, f2 m0sq, f2 S2, f2 D2, cplx& o0, cplx& o1){
  f2 m2 = m * m;
  f2 t  = m0sq - m2;
  f2 p  = (m2 - S2) * (m2 - D2);
  f2 pp = f2{ fmaxf(p.x, 0.f), fmaxf(p.y, 0.f) };
  f2 rs = f2{ __builtin_amdgcn_rsqf(pp.x), __builtin_amdgcn_rsqf(pp.y) };
  f2 r  = K * t * m2 * rs;
  float i0 = __builtin_amdgcn_rcpf(fmaf(r.x, r.x, 1.f));
  float i1 = __builtin_amdgcn_rcpf(fmaf(r.y, r.y, 1.f));
  o0 = { f2{ r.x * i0, i0 } };
  o1 = { f2{ r.y * i1, i1 } };
}
__device__ inline cplx bw_eval(float m, float K, float m0sq, float S2, float D2){
  float m2 = m * m;
  float t  = m0sq - m2;
  float p  = (m2 - S2) * (m2 - D2);
  float pp = fmaxf(p, 0.f);
  float r  = K * t * m2 * __builtin_amdgcn_rsqf(pp);
  float inv = __builtin_amdgcn_rcpf(fmaf(r, r, 1.f));
  return { f2{ r * inv, inv } };
}
__device__ inline cplx phase_neg(float phi){  // exp(-i*phi)
  return { f2{ __cosf(phi), -__sinf(phi) } };
}

// ================= per-event pipeline (R9 body, scalar inputs) =========
template<bool PRE>
__device__ __forceinline__ float event_amp(
    float mBC, float mBD, float mCD,
    float cBC, float cBBC, float pBC_, float pBBC,
    float cBD, float cDBD, float pDBD,
    float cCD, float cCCD, float pCD_, float pCCD,
    float cT1, float cT2, float p1_, float p2_,
    const float2* __restrict__ hs, const cplx* __restrict__ ht)
{
  // ---------- angles (u,v,hp); packed pairs over DIFFERENT angles ----------
  angp PBDT1  = mkang2(f2{ cBD, cT1  });   // (BD, T1)
  angp PT2CCD = mkang2(f2{ cT2, cCCD });   // (T2, CCD)
  angp PBCCD  = mkang2(f2{ cBC, cCD  });   // (BC, CD)
  angs SDBD   = mkang1(cDBD);
  angs SBBC   = mkang1(cBBC);

  // ---------- wigner tables ----------
  f2 dBDT1[2][3];
  static_for<0,2>([&](auto R_){ constexpr int r = decltype(R_)::value; constexpr int m1 = 2*r-1;
    static_for<-1,2>([&](auto M_){ constexpr int m2 = decltype(M_)::value;
      dBDT1[r][m2+1] = wig<1, m1, m2>(PBDT1); }); });
  f2 dT2CCD[3][3];
  static_for<-1,2>([&](auto M1_){ constexpr int m1 = decltype(M1_)::value;
    static_for<-1,2>([&](auto M2_){ constexpr int m2 = decltype(M2_)::value;
      dT2CCD[m1+1][m2+1] = wig<1, m1, m2>(PT2CCD); }); });
  f2 dBCCD[2][3];
  static_for<0,2>([&](auto A_){ constexpr int a = decltype(A_)::value; constexpr int lA = 2*a-1;
    static_for<-1,2>([&](auto M_){ constexpr int dm = decltype(M_)::value;
      dBCCD[a][dm+1] = wig<1, lA, dm>(PBCCD); }); });
  float dDBD[3][3], dBBC[5][2];
  static_for<-1,2>([&](auto M1_){ constexpr int m1 = decltype(M1_)::value;
    static_for<-1,2>([&](auto M2_){ constexpr int m2 = decltype(M2_)::value;
      dDBD[m1+1][m2+1] = wigs<1, m1, m2>(SDBD); }); });
  static_for<-2,3>([&](auto C_){ constexpr int lBC = decltype(C_)::value;
    static_for<0,2>([&](auto K_){ constexpr int k = decltype(K_)::value; constexpr int lB2 = 2*k-1;
      dBBC[lBC+2][k] = wigs<2, lBC, lB2>(SBBC); }); });

  // ---------- res0 spine: G0[a][(lD-lB)+1] (pre-scaled: P0 = dDBD*H10) ----------
  cplx G0[2][3];
  {
    cplx P0[3][3];
    static_for<-1,2>([&](auto L_){ constexpr int lDB = decltype(L_)::value;
      cplx h = GH(IH10(lDB));
      static_for<0,3>([&](auto M_){ constexpr int mi = decltype(M_)::value;
        P0[lDB+1][mi] = cscale(h, dDBD[lDB+1][mi]); }); });
    static_for<0,2>([&](auto A_){ constexpr int a = decltype(A_)::value;
      static_for<0,3>([&](auto M_){ constexpr int mi = decltype(M_)::value;
        cplx acc{ f2{0.f, 0.f} };
        static_for<-1,2>([&](auto L_){ constexpr int lDB = decltype(L_)::value;
          caxpy(acc, dBDT1[a][lDB+1].x, P0[lDB+1][mi]);
        });
        G0[a][mi] = acc; }); });
  }

  // ---------- res1 spine: V1[lB+1][lBC+2] (pre-scaled: Qm/Qp = dBBC*U1) ----------
  cplx V1[3][5];
  {
    cplx eP1 = phase_neg(p1_ + pBBC);
    cplx U1m = GH(IH21(-1)) * cconj(eP1);
    cplx U1p = GH(IH21( 1)) * eP1;
    cplx Qm[5], Qp[5];
    static_for<-2,3>([&](auto C_){ constexpr int lBC = decltype(C_)::value;
      Qm[lBC+2] = cscale(U1m, dBBC[lBC+2][0]);
      Qp[lBC+2] = cscale(U1p, dBBC[lBC+2][1]); });
    static_for<-1,2>([&](auto B_){ constexpr int lB = decltype(B_)::value;
      static_for<-2,3>([&](auto C_){ constexpr int lBC = decltype(C_)::value;
        cplx acc{ f2{0.f, 0.f} };
        caxpy(acc, dBDT1[0][lB+1].y, Qm[lBC+2]);
        caxpy(acc, dBDT1[1][lB+1].y, Qp[lBC+2]);
        V1[lB+1][lBC+2] = acc; }); });
  }

  // ---------- res2 spine: V2[lD+1][lCD+1] (pre-scaled: R2t = dCCD*U2) ----------
  cplx V2[3][3];
  {
    cplx eP2 = phase_neg(p2_ + pCCD);
    cplx U2[3];
    U2[0] = GH(IH22(-1)) * cconj(eP2);
    U2[1] = GH(IH22(0));
    U2[2] = GH(IH22(1)) * eP2;
    cplx R2t[3][3];
    static_for<-1,2>([&](auto C_){ constexpr int lCD = decltype(C_)::value;
      static_for<-1,2>([&](auto X_){ constexpr int lC2 = decltype(X_)::value;
        R2t[lCD+1][lC2+1] = cscale(U2[lC2+1], dT2CCD[lCD+1][lC2+1].y); }); });
    static_for<-1,2>([&](auto D_){ constexpr int lD = decltype(D_)::value;
      static_for<-1,2>([&](auto C_){ constexpr int lCD = decltype(C_)::value;
        cplx acc{ f2{0.f, 0.f} };
        static_for<-1,2>([&](auto X_){ constexpr int lC2 = decltype(X_)::value;
          caxpy(acc, dT2CCD[lC2+1][lD+1].x, R2t[lCD+1][lC2+1]);
        });
        V2[lD+1][lCD+1] = acc; }); });
  }

  // ---------- BW + phase folded coupling tables ----------
  cplx bw0, bw1;
  bw_eval2(f2{ mBD, mBC }, f2{K0, K1}, f2{M0SQ0, M0SQ1},
           f2{S2_0, S2_1}, f2{D2_0, D2_1}, bw0, bw1);
  const cplx bw2 = bw_eval(mCD, K2, M0SQ2, S2_2, D2_2);

  cplx W0T[3][3] = {};   // [lD+1][lB+1] : H2_0 * e_D^lD * bw0
  {
    const cplx eD = phase_neg(pDBD);
    cplx EBW0[3] = { cconj(eD) * bw0, bw0, eD * bw0 };
    static_for<-1,2>([&](auto D_){ constexpr int lD = decltype(D_)::value;
      static_for<-1,2>([&](auto B_){ constexpr int lB = decltype(B_)::value;
        if constexpr (cabs_i(lD - lB) <= 1 && hnz<1,1,1,1,lD,lB>())
          W0T[lD+1][lB+1] = GH(IH20(lD,lB)) * EBW0[lD+1];
      }); });
  }
  cplx HT1[5][3] = {};   // [lBC+2][lD+1] : H1_1 * e_BC^lBC * bw1
  {
    const cplx eBC = phase_neg(pBC_);
    const cplx e2  = eBC * eBC;
    cplx T1B[5] = { cconj(e2) * bw1, cconj(eBC) * bw1, bw1, eBC * bw1, e2 * bw1 };
    static_for<-2,3>([&](auto C_){ constexpr int lBC = decltype(C_)::value;
      static_for<-1,2>([&](auto D_){ constexpr int lD = decltype(D_)::value;
        if constexpr (cabs_i(lBC - lD) <= 1 && hnz<2,1,2,1,lBC,lD>())
          HT1[lBC+2][lD+1] = GH(IH11(lBC,lD)) * T1B[lBC+2];
      }); });
  }
  cplx HT2[3][3] = {};   // [lCD+1][lB+1] : H1_2 * e_CD^lCD * bw2
  {
    const cplx eCD = phase_neg(pCD_);
    cplx T2B[3] = { cconj(eCD) * bw2, bw2, eCD * bw2 };
    static_for<-1,2>([&](auto C_){ constexpr int lCD = decltype(C_)::value;
      static_for<-1,2>([&](auto B_){ constexpr int lB = decltype(B_)::value;
        if constexpr (cabs_i(lCD - lB) <= 1 && hnz<4,1,1,1,lCD,lB>())
          HT2[lCD+1][lB+1] = GH(IH12(lCD,lB)) * T2B[lCD+1];
      }); });
  }

  // ---------- 18-combo helicity sum (packed |amp|^2 accumulators) ----------
  f2 t0 = {0.f, 0.f}, t1 = {0.f, 0.f};
  static_for<-1,2>([&](auto B_){ constexpr int lB = decltype(B_)::value;
    static_for<-1,2>([&](auto D_){ constexpr int lD = decltype(D_)::value;
      cplx Y1[3] = {};
      static_for<-1,2>([&](auto M_){ constexpr int dm = decltype(M_)::value; constexpr int lBC = lD + dm;
        if constexpr (hnz<2,1,2,1,lBC,lD>())
          Y1[dm+1] = HT1[lBC+2][lD+1] * V1[lB+1][lBC+2];
      });
      cplx Y2[3] = {};
      static_for<-1,2>([&](auto M_){ constexpr int dm = decltype(M_)::value; constexpr int lCD = lB + dm;
        if constexpr (cabs_i(lCD) <= 1 && hnz<4,1,1,1,lCD,lB>())
          Y2[dm+1] = HT2[lCD+1][lB+1] * V2[lD+1][lCD+1];
      });
      static_for<0,2>([&](auto A_){ constexpr int a = decltype(A_)::value;
        cplx amp{ f2{0.f, 0.f} };
        if constexpr (cabs_i(lD - lB) <= 1 && hnz<1,1,1,1,lD,lB>())
          amp = W0T[lD+1][lB+1] * G0[a][lD-lB+1];
        static_for<-1,2>([&](auto M_){ constexpr int dm = decltype(M_)::value; constexpr int lBC = lD + dm;
          if constexpr (hnz<2,1,2,1,lBC,lD>())
            caxpy(amp, dBCCD[a][dm+1].x, Y1[dm+1]);
        });
        static_for<-1,2>([&](auto M_){ constexpr int dm = decltype(M_)::value; constexpr int lCD = lB + dm;
          if constexpr (cabs_i(lCD) <= 1 && hnz<4,1,1,1,lCD,lB>())
            caxpy(amp, dBCCD[a][dm+1].y, Y2[dm+1]);
        });
        if constexpr (a == 0) t0 = vfma2(amp.v, amp.v, t0);
        else                  t1 = vfma2(amp.v, amp.v, t1);
      });
    });
  });

  return (t0.x + t0.y) + (t1.x + t1.y);
}

// ================= pre-kernel: uniform H couplings -> d_ws =================
__global__ void prep_htab_kernel(const float2* __restrict__ g_par, float2* __restrict__ ws){
  if (blockIdx.x != 0 || threadIdx.x != 0) return;
  cplx t[NH];
  compute_htab(g_par, t);
  #pragma unroll
  for (int k = 0; k < NH; ++k) ws[k] = make_float2(t[k].v.x, t[k].v.y);
}

// ================= main kernel: 2 events per thread, serial pipelines ====
template<bool PRE>
__global__ void __launch_bounds__(256)
AllAmplitude_59665685676511_kernel(
    const float* __restrict__ g_mBC,  const float* __restrict__ g_mBD,  const float* __restrict__ g_mCD,
    const float* __restrict__ g_cBC,  const float* __restrict__ g_cBBC, const float* __restrict__ g_pBC,  const float* __restrict__ g_pBBC,
    const float* __restrict__ g_cBD,  const float* __restrict__ g_cDBD, const float* __restrict__ g_pDBD,
    const float* __restrict__ g_cCD,  const float* __restrict__ g_cCCD, const float* __restrict__ g_pCD,  const float* __restrict__ g_pCCD,
    const float* __restrict__ g_cT1,  const float* __restrict__ g_cT2,  const float* __restrict__ g_p1,   const float* __restrict__ g_p2,
    const float2* __restrict__ g_par, const float2* __restrict__ hs,
    float* __restrict__ out, int n)
{
  const int base = (blockIdx.x * 256 + threadIdx.x) * 2;
  if (base >= n) return;
  const bool full = (base + 1) < n;

  cplx ht[NH];
  if constexpr (!PRE) compute_htab(g_par, ht);

  auto ld = [&](const float* __restrict__ p) -> f2 {
    if (full){ float2 t = *reinterpret_cast<const float2*>(p + base); return f2{t.x, t.y}; }
    float t = p[base]; return f2{t, t};
  };

  // hoist all 19 inputs as dwordx2 pairs
  f2 LmBC = ld(g_mBC),  LmBD = ld(g_mBD),  LmCD = ld(g_mCD);
  f2 LcBC = ld(g_cBC),  LcBBC = ld(g_cBBC), LpBC = ld(g_pBC),  LpBBC = ld(g_pBBC);
  f2 LcBD = ld(g_cBD),  LcDBD = ld(g_cDBD), LpDBD = ld(g_pDBD);
  f2 LcCD = ld(g_cCD),  LcCCD = ld(g_cCCD), LpCD = ld(g_pCD),  LpCCD = ld(g_pCCD);
  f2 LcT1 = ld(g_cT1),  LcT2 = ld(g_cT2),   Lp1  = ld(g_p1),   Lp2  = ld(g_p2);

  float o0 = event_amp<PRE>(
      LmBC.x, LmBD.x, LmCD.x,
      LcBC.x, LcBBC.x, LpBC.x, LpBBC.x,
      LcBD.x, LcDBD.x, LpDBD.x,
      LcCD.x, LcCCD.x, LpCD.x, LpCCD.x,
      LcT1.x, LcT2.x, Lp1.x, Lp2.x, hs, ht);

  if (full) {
    float o1 = event_amp<PRE>(
        LmBC.y, LmBD.y, LmCD.y,
        LcBC.y, LcBBC.y, LpBC.y, LpBBC.y,
        LcBD.y, LcDBD.y, LpDBD.y,
        LcCD.y, LcCCD.y, LpCD.y, LpCCD.y,
        LcT1.y, LcT2.y, Lp1.y, Lp2.y, hs, ht);
    *reinterpret_cast<float2*>(out + base) = make_float2(o0, o1);
  } else {
    out[base] = o0;
  }
}

// ================= launch =================
extern "C" void kernel_launch(void* const* d_in, const int* in_sizes, int n_in,
                              void* d_out, int out_size, void* d_ws, size_t ws_size,
                              hipStream_t stream) {
  (void)n_in; (void)out_size;
  const int n = in_sizes[0];
  const float*  mBC  = (const float*)d_in[0];
  const float*  mBD  = (const float*)d_in[1];
  const float*  mCD  = (const float*)d_in[2];
  const float*  cBC  = (const float*)d_in[3];
  const float*  cBBC = (const float*)d_in[4];
  const float*  pBC  = (const float*)d_in[5];
  const float*  pBBC = (const float*)d_in[6];
  const float*  cBD  = (const float*)d_in[7];
  const float*  cDBD = (const float*)d_in[8];
  const float*  pDBD = (const float*)d_in[9];
  const float*  cCD  = (const float*)d_in[10];
  const float*  cCCD = (const float*)d_in[11];
  const float*  pCD  = (const float*)d_in[12];
  const float*  pCCD = (const float*)d_in[13];
  const float*  cT1  = (const float*)d_in[14];
  const float*  cT2  = (const float*)d_in[15];
  const float*  p1   = (const float*)d_in[16];
  const float*  p2   = (const float*)d_in[17];
  const float2* parm = (const float2*)d_in[18];

  const int npair = (n + 1) / 2;
  dim3 block(256);
  dim3 grid((npair + 255) / 256);

  if (ws_size >= NH * sizeof(float2)) {
    prep_htab_kernel<<<1, 64, 0, stream>>>(parm, (float2*)d_ws);
    AllAmplitude_59665685676511_kernel<true><<<grid, block, 0, stream>>>(
        mBC, mBD, mCD, cBC, cBBC, pBC, pBBC, cBD, cDBD, pDBD,
        cCD, cCCD, pCD, pCCD, cT1, cT2, p1, p2, parm,
        (const float2*)d_ws, (float*)d_out, n);
  } else {
    AllAmplitude_59665685676511_kernel<false><<<grid, block, 0, stream>>>(
        mBC, mBD, mCD, cBC, cBBC, pBC, pBBC, cBD, cDBD, pDBD,
        cCD, cCCD, pCD, pCCD, cT1, cT2, p1, p2, parm,
        nullptr, (float*)d_out, n);
  }
}

// Round 12
// 47.061 us; speedup vs baseline: 1.2358x; 1.2358x over previous
//
#include <hip/hip_runtime.h>
#include <utility>
#include <type_traits>

typedef float f2 __attribute__((ext_vector_type(2)));

// ================= compile-time math (mirrors reference) =================
constexpr int cabs_i(int x){ return x < 0 ? -x : x; }
constexpr int cmax_i(int a, int b){ return a > b ? a : b; }
constexpr int cmin_i(int a, int b){ return a < b ? a : b; }
constexpr double cfact(int n){ double r = 1.0; for (int i = 2; i <= n; ++i) r *= (double)i; return r; }
constexpr double csqrt_d(double x){
  if (x <= 0.0) return 0.0;
  double r = x > 1.0 ? x : 1.0;
  for (int i = 0; i < 64; ++i) r = 0.5 * (r + x / r);
  return r;
}
constexpr double cg_coef(int j1,int j2,int m1,int m2,int j,int m){
  if (m1 + m2 != m || j < cabs_i(j1 - j2) || j > j1 + j2) return 0.0;
  if (cabs_i(m1) > j1 || cabs_i(m2) > j2 || cabs_i(m) > j) return 0.0;
  double pref = csqrt_d((2.0*j + 1.0) * cfact(j1+j2-j) * cfact(j+j1-j2) * cfact(j+j2-j1) / cfact(j1+j2+j+1));
  pref *= csqrt_d(cfact(j+m)*cfact(j-m)*cfact(j1-m1)*cfact(j1+m1)*cfact(j2-m2)*cfact(j2+m2));
  double s = 0.0;
  const int k0 = cmax_i(0, cmax_i(j2-j-m1, j1+m2-j));
  const int k1 = cmin_i(j1+j2-j, cmin_i(j1-m1, j2+m2));
  for (int k = k0; k <= k1; ++k){
    double t = 1.0/(cfact(k)*cfact(j1+j2-j-k)*cfact(j1-m1-k)*cfact(j2+m2-k)*cfact(j-j2+m1+k)*cfact(j-j1-m2+k));
    s += (k & 1) ? -t : t;
  }
  return pref * s;
}
constexpr double wd_coef(int j,int m1,int m2,int s){
  double pref = csqrt_d(cfact(j+m1)*cfact(j-m1)*cfact(j+m2)*cfact(j-m2));
  double c = pref / (cfact(j+m2-s)*cfact(s)*cfact(m1-m2+s)*cfact(j-m1-s));
  return ((m1-m2+s) & 1) ? -c : c;
}
constexpr double cgetp(double M0,double M1,double M2){
  double s = M1+M2, d = M1-M2;
  double p = (M0-s)*(M0+s)*(M0-d)*(M0+d);
  double pp = 0.5*(p + (p < 0 ? -p : p));
  return csqrt_d(pp)/(2.0*M0);
}

// ================= static_for =================
template<int Start, class F, int... Is>
__device__ inline void static_for_impl(F&& f, std::integer_sequence<int, Is...>){
  (f(std::integral_constant<int, Start + Is>{}), ...);
}
template<int Start, int End, class F>   // [Start, End)
__device__ inline void static_for(F&& f){
  if constexpr (End > Start)
    static_for_impl<Start>(static_cast<F&&>(f), std::make_integer_sequence<int, End - Start>{});
}

// ================= packed complex (re,im in one f2 -> v_pk_* ops) =======
__device__ inline f2 vfma2(f2 a, f2 b, f2 c){ return __builtin_elementwise_fma(a, b, c); }

struct cplx { f2 v; };   // v.x = re, v.y = im
__device__ inline cplx operator+(cplx a, cplx b){ return { a.v + b.v }; }
__device__ inline cplx operator*(cplx a, cplx b){
  f2 sw  = { -a.v.y, a.v.x };
  f2 bre = {  b.v.x, b.v.x };
  f2 bim = {  b.v.y, b.v.y };
  return { vfma2(a.v, bre, sw * bim) };   // 2 packed ops
}
__device__ inline cplx cconj(cplx a){ return { f2{ a.v.x, -a.v.y } }; }
__device__ inline cplx cscale(cplx x, float r){ return { x.v * f2{r, r} }; }  // 1 pk_mul
__device__ inline void caxpy(cplx& acc, float r, cplx x){   // 1 packed fma
  acc.v = vfma2(f2{r, r}, x.v, acc.v);
}

template<int n> __device__ inline float spow(float x){
  if constexpr (n <= 0) return 1.f;
  else return x * spow<n-1>(x);
}
template<int n> __device__ inline f2 vpow(f2 x){
  if constexpr (n <= 0) return f2{1.f, 1.f};
  else return x * vpow<n-1>(x);
}

// ================= wigner d in (u, v, hp) basis =========================
// u=(1+c)/2=ch^2, v=(1-c)/2=sh^2, hp=sqrt(uv)=ch*sh  (theta in [0,pi] -> hp>=0)
struct angs { float u, v, hp; };
__device__ inline angs mkang1(float c){
  angs A;
  A.u = (1.f + c) * 0.5f;
  A.v = (1.f - c) * 0.5f;
  A.hp = __builtin_amdgcn_sqrtf(A.u * A.v);
  return A;
}
struct angp { f2 u, v, hp; };   // packed over TWO DIFFERENT ANGLES
__device__ inline angp mkang2(f2 c){
  angp A;
  A.u = (c + 1.f) * 0.5f;
  A.v = (1.f - c) * 0.5f;
  f2 p = A.u * A.v;
  A.hp = f2{ __builtin_amdgcn_sqrtf(p.x), __builtin_amdgcn_sqrtf(p.y) };
  return A;
}
template<int j, int m1, int m2>
__device__ inline float wigs(const angs& A){
  constexpr int s0 = cmax_i(0, m2 - m1);
  constexpr int s1 = cmin_i(j - m1, j + m2);
  float out = 0.f;
  static_for<s0, s1 + 1>([&](auto S){
    constexpr int s = decltype(S)::value;
    constexpr float coef = (float)wd_coef(j, m1, m2, s);
    constexpr int P = 2*j + m2 - m1 - 2*s;
    constexpr int Q = m1 - m2 + 2*s;
    float mono;
    if constexpr (P & 1) mono = A.hp * spow<(P-1)/2>(A.u) * spow<(Q-1)/2>(A.v);
    else                 mono = spow<P/2>(A.u) * spow<Q/2>(A.v);
    out = fmaf(coef, mono, out);
  });
  return out;
}
template<int j, int m1, int m2>
__device__ inline f2 wig(const angp& A){
  constexpr int s0 = cmax_i(0, m2 - m1);
  constexpr int s1 = cmin_i(j - m1, j + m2);
  f2 out = {0.f, 0.f};
  static_for<s0, s1 + 1>([&](auto S){
    constexpr int s = decltype(S)::value;
    constexpr float coef = (float)wd_coef(j, m1, m2, s);
    constexpr int P = 2*j + m2 - m1 - 2*s;
    constexpr int Q = m1 - m2 + 2*s;
    f2 mono;
    if constexpr (P & 1) mono = A.hp * vpow<(P-1)/2>(A.u) * vpow<(Q-1)/2>(A.v);
    else                 mono = vpow<P/2>(A.u) * vpow<Q/2>(A.v);
    out = vfma2(f2{coef, coef}, mono, out);
  });
  return out;
}

// ================= static LS layout (from reference _build_layout) =====
struct LS { int l, s; };
template<int E> struct Entry;
template<> struct Entry<0>{ static constexpr int off = 0;  static constexpr int n = 2; static constexpr LS ls[2] = {{0,1},{2,1}}; };
template<> struct Entry<1>{ static constexpr int off = 2;  static constexpr int n = 3; static constexpr LS ls[3] = {{0,1},{2,1},{2,2}}; };
template<> struct Entry<2>{ static constexpr int off = 5;  static constexpr int n = 5; static constexpr LS ls[5] = {{0,1},{2,1},{2,2},{2,3},{4,3}}; };
template<> struct Entry<3>{ static constexpr int off = 10; static constexpr int n = 1; static constexpr LS ls[1] = {{2,1}}; };
template<> struct Entry<4>{ static constexpr int off = 11; static constexpr int n = 3; static constexpr LS ls[3] = {{0,1},{2,1},{2,2}}; };
template<> struct Entry<5>{ static constexpr int off = 14; static constexpr int n = 2; static constexpr LS ls[2] = {{0,1},{2,1}}; };

template<int E,int ja,int jb,int jc,int lb,int lc>
constexpr double hcoef(int idx){
  return cg_coef(jb, jc, lb, -lc, Entry<E>::ls[idx].s, lb - lc)
       * cg_coef(Entry<E>::ls[idx].l, Entry<E>::ls[idx].s, 0, lb - lc, ja, lb - lc);
}
template<int E,int ja,int jb,int jc,int lb,int lc>
constexpr bool hnz(){
  bool any = false;
  for (int i = 0; i < Entry<E>::n; ++i) if (hcoef<E,ja,jb,jc,lb,lc>(i) != 0.0) any = true;
  return any;
}
template<int E,int ja,int jb,int jc,int lb,int lc>
__device__ inline cplx H_ls(const cplx* par){
  cplx tot{ f2{0.f, 0.f} };
  static_for<0, Entry<E>::n>([&](auto I){
    constexpr double c = hcoef<E,ja,jb,jc,lb,lc>(decltype(I)::value);
    if constexpr (c != 0.0){
      caxpy(tot, (float)c, par[Entry<E>::off + decltype(I)::value]);
    }
  });
  return tot;
}

// ================= H table layout in d_ws =================
constexpr int IH10(int lDB){ return lDB+1; }                       // 0..2
constexpr int IH20(int lD,int lB){ return 3+(lD+1)*3+(lB+1); }     // 3..11
constexpr int IH11(int lBC,int lD){ return 12+(lBC+2)*3+(lD+1); }  // 12..26
constexpr int IH21(int lB2){ return 27+(lB2+1)/2; }                // 27..28
constexpr int IH12(int lCD,int lB){ return 29+(lCD+1)*3+(lB+1); }  // 29..37
constexpr int IH22(int lC2){ return 38+(lC2+1); }                  // 38..40
constexpr int NH = 41;

__device__ inline void compute_htab(const float2* __restrict__ g_par, cplx* t){
  cplx par[16];
  #pragma unroll
  for (int k = 0; k < 16; ++k){ float2 p = g_par[k]; par[k].v = f2{p.x, p.y}; }
  static_for<-1,2>([&](auto L){ constexpr int l = decltype(L)::value; t[IH10(l)] = H_ls<0,1,1,0,l,0>(par); });
  static_for<-1,2>([&](auto D){ constexpr int lD = decltype(D)::value;
    static_for<-1,2>([&](auto B){ constexpr int lB = decltype(B)::value;
      t[IH20(lD,lB)] = H_ls<1,1,1,1,lD,lB>(par); }); });
  static_for<-2,3>([&](auto C){ constexpr int lBC = decltype(C)::value;
    static_for<-1,2>([&](auto D){ constexpr int lD = decltype(D)::value;
      t[IH11(lBC,lD)] = H_ls<2,1,2,1,lBC,lD>(par); }); });
  t[IH21(-1)] = H_ls<3,2,1,0,-1,0>(par);
  t[IH21( 1)] = H_ls<3,2,1,0, 1,0>(par);
  static_for<-1,2>([&](auto C){ constexpr int lCD = decltype(C)::value;
    static_for<-1,2>([&](auto B){ constexpr int lB = decltype(B)::value;
      t[IH12(lCD,lB)] = H_ls<4,1,1,1,lCD,lB>(par); }); });
  static_for<-1,2>([&](auto C){ constexpr int lC2 = decltype(C)::value;
    t[IH22(lC2)] = H_ls<5,1,0,1,0,lC2>(par); });
}

template<int IDX, bool PRE>
__device__ inline cplx getH(const float2* __restrict__ hs, const cplx* ht){
  if constexpr (PRE){ float2 v = hs[IDX]; return cplx{ f2{v.x, v.y} }; }
  else return ht[IDX];
}
#define GH(IDX) getH<(IDX), PRE>(hs, ht)

// ================= physics constants =================
constexpr double dM0B = 2.01026, dM0C = 0.13957061, dM0D = 2.00685;
constexpr double dR0m0 = 4.026,  dR0g0 = 0.025;    // BD chain, J=1
constexpr double dR1m0 = 2.4607, dR1g0 = 0.0475;   // BC chain, J=2
constexpr double dR2m0 = 2.4232, dR2g0 = 0.025;    // CD chain, J=1

constexpr float M0SQ0 = (float)(dR0m0*dR0m0);
constexpr float M0SQ1 = (float)(dR1m0*dR1m0);
constexpr float M0SQ2 = (float)(dR2m0*dR2m0);
constexpr float S2_0 = (float)((dM0B+dM0D)*(dM0B+dM0D)), D2_0 = (float)((dM0B-dM0D)*(dM0B-dM0D));
constexpr float S2_1 = (float)((dM0B+dM0C)*(dM0B+dM0C)), D2_1 = (float)((dM0B-dM0C)*(dM0B-dM0C));
constexpr float S2_2 = (float)((dM0C+dM0D)*(dM0C+dM0D)), D2_2 = (float)((dM0C-dM0D)*(dM0C-dM0D));
constexpr float K0 = (float)(2.0 * cgetp(dR0m0, dM0B, dM0D) / (dR0g0 * dR0m0 * dR0m0));
constexpr float K1 = (float)(2.0 * cgetp(dR1m0, dM0B, dM0C) / (dR1g0 * dR1m0 * dR1m0));
constexpr float K2 = (float)(2.0 * cgetp(dR2m0, dM0C, dM0D) / (dR2g0 * dR2m0 * dR2m0));

__device__ inline void bw_eval2(f2 m, f2 K, f2 m0sq, f2 S2, f2 D2, cplx& o0, cplx& o1){
  f2 m2 = m * m;
  f2 t  = m0sq - m2;
  f2 p  = (m2 - S2) * (m2 - D2);
  f2 pp = f2{ fmaxf(p.x, 0.f), fmaxf(p.y, 0.f) };
  f2 rs = f2{ __builtin_amdgcn_rsqf(pp.x), __builtin_amdgcn_rsqf(pp.y) };
  f2 r  = K * t * m2 * rs;
  float i0 = __builtin_amdgcn_rcpf(fmaf(r.x, r.x, 1.f));
  float i1 = __builtin_amdgcn_rcpf(fmaf(r.y, r.y, 1.f));
  o0 = { f2{ r.x * i0, i0 } };
  o1 = { f2{ r.y * i1, i1 } };
}
__device__ inline cplx bw_eval(float m, float K, float m0sq, float S2, float D2){
  float m2 = m * m;
  float t  = m0sq - m2;
  float p  = (m2 - S2) * (m2 - D2);
  float pp = fmaxf(p, 0.f);
  float r  = K * t * m2 * __builtin_amdgcn_rsqf(pp);
  float inv = __builtin_amdgcn_rcpf(fmaf(r, r, 1.f));
  return { f2{ r * inv, inv } };
}
__device__ inline cplx phase_neg(float phi){  // exp(-i*phi)
  return { f2{ __cosf(phi), -__sinf(phi) } };
}

// ================= pre-kernel: uniform H couplings -> d_ws =================
__global__ void prep_htab_kernel(const float2* __restrict__ g_par, float2* __restrict__ ws){
  if (blockIdx.x != 0 || threadIdx.x != 0) return;
  cplx t[NH];
  compute_htab(g_par, t);
  #pragma unroll
  for (int k = 0; k < NH; ++k) ws[k] = make_float2(t[k].v.x, t[k].v.y);
}

// ================= main kernel =================
template<bool PRE>
__global__ void __launch_bounds__(256, 4)
AllAmplitude_59665685676511_kernel(
    const float* __restrict__ g_mBC,  const float* __restrict__ g_mBD,  const float* __restrict__ g_mCD,
    const float* __restrict__ g_cBC,  const float* __restrict__ g_cBBC, const float* __restrict__ g_pBC,  const float* __restrict__ g_pBBC,
    const float* __restrict__ g_cBD,  const float* __restrict__ g_cDBD, const float* __restrict__ g_pDBD,
    const float* __restrict__ g_cCD,  const float* __restrict__ g_cCCD, const float* __restrict__ g_pCD,  const float* __restrict__ g_pCCD,
    const float* __restrict__ g_cT1,  const float* __restrict__ g_cT2,  const float* __restrict__ g_p1,   const float* __restrict__ g_p2,
    const float2* __restrict__ g_par, const float2* __restrict__ hs,
    float* __restrict__ out, int n)
{
  int i = blockIdx.x * 256 + threadIdx.x;
  if (i >= n) return;

  cplx ht[NH];
  if constexpr (!PRE) compute_htab(g_par, ht);

  // ---------- angles (u,v,hp); packed pairs over DIFFERENT angles ----------
  angp PBDT1  = mkang2(f2{ g_cBD[i], g_cT1[i]  });   // (BD, T1)
  angp PT2CCD = mkang2(f2{ g_cT2[i], g_cCCD[i] });   // (T2, CCD)
  angp PBCCD  = mkang2(f2{ g_cBC[i], g_cCD[i]  });   // (BC, CD)
  angs SDBD   = mkang1(g_cDBD[i]);
  angs SBBC   = mkang1(g_cBBC[i]);

  // ---------- wigner tables ----------
  f2 dBDT1[2][3];
  static_for<0,2>([&](auto R_){ constexpr int r = decltype(R_)::value; constexpr int m1 = 2*r-1;
    static_for<-1,2>([&](auto M_){ constexpr int m2 = decltype(M_)::value;
      dBDT1[r][m2+1] = wig<1, m1, m2>(PBDT1); }); });
  f2 dT2CCD[3][3];
  static_for<-1,2>([&](auto M1_){ constexpr int m1 = decltype(M1_)::value;
    static_for<-1,2>([&](auto M2_){ constexpr int m2 = decltype(M2_)::value;
      dT2CCD[m1+1][m2+1] = wig<1, m1, m2>(PT2CCD); }); });
  f2 dBCCD[2][3];
  static_for<0,2>([&](auto A_){ constexpr int a = decltype(A_)::value; constexpr int lA = 2*a-1;
    static_for<-1,2>([&](auto M_){ constexpr int dm = decltype(M_)::value;
      dBCCD[a][dm+1] = wig<1, lA, dm>(PBCCD); }); });
  float dDBD[3][3], dBBC[5][2];
  static_for<-1,2>([&](auto M1_){ constexpr int m1 = decltype(M1_)::value;
    static_for<-1,2>([&](auto M2_){ constexpr int m2 = decltype(M2_)::value;
      dDBD[m1+1][m2+1] = wigs<1, m1, m2>(SDBD); }); });
  static_for<-2,3>([&](auto C_){ constexpr int lBC = decltype(C_)::value;
    static_for<0,2>([&](auto K_){ constexpr int k = decltype(K_)::value; constexpr int lB2 = 2*k-1;
      dBBC[lBC+2][k] = wigs<2, lBC, lB2>(SBBC); }); });

  // ---------- Breit-Wigners ----------
  cplx bw0, bw1;
  bw_eval2(f2{ g_mBD[i], g_mBC[i] }, f2{K0, K1}, f2{M0SQ0, M0SQ1},
           f2{S2_0, S2_1}, f2{D2_0, D2_1}, bw0, bw1);
  const cplx bw2 = bw_eval(g_mCD[i], K2, M0SQ2, S2_2, D2_2);

  // ---------- res1: HT1 then rank-2 contraction into Am/Ap ----------
  // ar1(a,lB,lD) = dT1m[lB]*Am[a][lD] + dT1p[lB]*Ap[a][lD]
  cplx Am[2][3], Ap[2][3];
  {
    cplx HT1[5][3] = {};   // [lBC+2][lD+1] : H1_1 * e_BC^lBC * bw1
    {
      const cplx eBC = phase_neg(g_pBC[i]);
      const cplx e2  = eBC * eBC;
      cplx T1B[5] = { cconj(e2) * bw1, cconj(eBC) * bw1, bw1, eBC * bw1, e2 * bw1 };
      static_for<-2,3>([&](auto C_){ constexpr int lBC = decltype(C_)::value;
        static_for<-1,2>([&](auto D_){ constexpr int lD = decltype(D_)::value;
          if constexpr (cabs_i(lBC - lD) <= 1 && hnz<2,1,2,1,lBC,lD>())
            HT1[lBC+2][lD+1] = GH(IH11(lBC,lD)) * T1B[lBC+2];
        }); });
    }
    cplx eP1 = phase_neg(g_p1[i] + g_pBBC[i]);
    cplx U1m = GH(IH21(-1)) * cconj(eP1);
    cplx U1p = GH(IH21( 1)) * eP1;
    // Tm/Tp[lBC][lD] = HT1 * (U1 * dBBC)
    cplx Qm[5], Qp[5];
    static_for<-2,3>([&](auto C_){ constexpr int lBC = decltype(C_)::value;
      Qm[lBC+2] = cscale(U1m, dBBC[lBC+2][0]);
      Qp[lBC+2] = cscale(U1p, dBBC[lBC+2][1]); });
    cplx Tm[5][3], Tp[5][3];
    static_for<-2,3>([&](auto C_){ constexpr int lBC = decltype(C_)::value;
      static_for<-1,2>([&](auto D_){ constexpr int lD = decltype(D_)::value;
        if constexpr (cabs_i(lBC - lD) <= 1 && hnz<2,1,2,1,lBC,lD>()){
          Tm[lBC+2][lD+1] = HT1[lBC+2][lD+1] * Qm[lBC+2];
          Tp[lBC+2][lD+1] = HT1[lBC+2][lD+1] * Qp[lBC+2];
        }
      }); });
    static_for<0,2>([&](auto A_){ constexpr int a = decltype(A_)::value;
      static_for<-1,2>([&](auto D_){ constexpr int lD = decltype(D_)::value;
        cplx am{ f2{0.f,0.f} }, ap{ f2{0.f,0.f} };
        static_for<-1,2>([&](auto M_){ constexpr int dm = decltype(M_)::value; constexpr int lBC = lD + dm;
          if constexpr (hnz<2,1,2,1,lBC,lD>()){
            caxpy(am, dBCCD[a][dm+1].x, Tm[lBC+2][lD+1]);
            caxpy(ap, dBCCD[a][dm+1].x, Tp[lBC+2][lD+1]);
          }
        });
        Am[a][lD+1] = am;
        Ap[a][lD+1] = ap;
      }); });
  }

  // ---------- res0 spine: G0[a][(lD-lB)+1] (pre-scaled: P0 = dDBD*H10) ----------
  cplx G0[2][3];
  {
    cplx P0[3][3];
    static_for<-1,2>([&](auto L_){ constexpr int lDB = decltype(L_)::value;
      cplx h = GH(IH10(lDB));
      static_for<0,3>([&](auto M_){ constexpr int mi = decltype(M_)::value;
        P0[lDB+1][mi] = cscale(h, dDBD[lDB+1][mi]); }); });
    static_for<0,2>([&](auto A_){ constexpr int a = decltype(A_)::value;
      static_for<0,3>([&](auto M_){ constexpr int mi = decltype(M_)::value;
        cplx acc{ f2{0.f, 0.f} };
        static_for<-1,2>([&](auto L_){ constexpr int lDB = decltype(L_)::value;
          caxpy(acc, dBDT1[a][lDB+1].x, P0[lDB+1][mi]);
        });
        G0[a][mi] = acc; }); });
  }

  // ---------- res2 spine: V2[lD+1][lCD+1] (pre-scaled: R2t = dCCD*U2) ----------
  cplx V2[3][3];
  {
    cplx eP2 = phase_neg(g_p2[i] + g_pCCD[i]);
    cplx U2[3];
    U2[0] = GH(IH22(-1)) * cconj(eP2);
    U2[1] = GH(IH22(0));
    U2[2] = GH(IH22(1)) * eP2;
    cplx R2t[3][3];
    static_for<-1,2>([&](auto C_){ constexpr int lCD = decltype(C_)::value;
      static_for<-1,2>([&](auto X_){ constexpr int lC2 = decltype(X_)::value;
        R2t[lCD+1][lC2+1] = cscale(U2[lC2+1], dT2CCD[lCD+1][lC2+1].y); }); });
    static_for<-1,2>([&](auto D_){ constexpr int lD = decltype(D_)::value;
      static_for<-1,2>([&](auto C_){ constexpr int lCD = decltype(C_)::value;
        cplx acc{ f2{0.f, 0.f} };
        static_for<-1,2>([&](auto X_){ constexpr int lC2 = decltype(X_)::value;
          caxpy(acc, dT2CCD[lC2+1][lD+1].x, R2t[lCD+1][lC2+1]);
        });
        V2[lD+1][lCD+1] = acc; }); });
  }

  // ---------- remaining coupling tables ----------
  cplx W0T[3][3] = {};   // [lD+1][lB+1] : H2_0 * e_D^lD * bw0
  {
    const cplx eD = phase_neg(g_pDBD[i]);
    cplx EBW0[3] = { cconj(eD) * bw0, bw0, eD * bw0 };
    static_for<-1,2>([&](auto D_){ constexpr int lD = decltype(D_)::value;
      static_for<-1,2>([&](auto B_){ constexpr int lB = decltype(B_)::value;
        if constexpr (cabs_i(lD - lB) <= 1 && hnz<1,1,1,1,lD,lB>())
          W0T[lD+1][lB+1] = GH(IH20(lD,lB)) * EBW0[lD+1];
      }); });
  }
  cplx HT2[3][3] = {};   // [lCD+1][lB+1] : H1_2 * e_CD^lCD * bw2
  {
    const cplx eCD = phase_neg(g_pCD[i]);
    cplx T2B[3] = { cconj(eCD) * bw2, bw2, eCD * bw2 };
    static_for<-1,2>([&](auto C_){ constexpr int lCD = decltype(C_)::value;
      static_for<-1,2>([&](auto B_){ constexpr int lB = decltype(B_)::value;
        if constexpr (cabs_i(lCD - lB) <= 1 && hnz<4,1,1,1,lCD,lB>())
          HT2[lCD+1][lB+1] = GH(IH12(lCD,lB)) * T2B[lCD+1];
      }); });
  }

  // ---------- 18-combo helicity sum ----------
  f2 t0 = {0.f, 0.f}, t1 = {0.f, 0.f};
  static_for<-1,2>([&](auto B_){ constexpr int lB = decltype(B_)::value;
    const float dT1m = dBDT1[0][lB+1].y;
    const float dT1p = dBDT1[1][lB+1].y;
    static_for<-1,2>([&](auto D_){ constexpr int lD = decltype(D_)::value;
      cplx Y2[3] = {};
      static_for<-1,2>([&](auto M_){ constexpr int dm = decltype(M_)::value; constexpr int lCD = lB + dm;
        if constexpr (cabs_i(lCD) <= 1 && hnz<4,1,1,1,lCD,lB>())
          Y2[dm+1] = HT2[lCD+1][lB+1] * V2[lD+1][lCD+1];
      });
      static_for<0,2>([&](auto A_){ constexpr int a = decltype(A_)::value;
        cplx amp{ f2{0.f, 0.f} };
        if constexpr (cabs_i(lD - lB) <= 1 && hnz<1,1,1,1,lD,lB>())
          amp = W0T[lD+1][lB+1] * G0[a][lD-lB+1];
        // res1 (rank-2 factor)
        caxpy(amp, dT1m, Am[a][lD+1]);
        caxpy(amp, dT1p, Ap[a][lD+1]);
        // res2
        static_for<-1,2>([&](auto M_){ constexpr int dm = decltype(M_)::value; constexpr int lCD = lB + dm;
          if constexpr (cabs_i(lCD) <= 1 && hnz<4,1,1,1,lCD,lB>())
            caxpy(amp, dBCCD[a][dm+1].y, Y2[dm+1]);
        });
        if constexpr (a == 0) t0 = vfma2(amp.v, amp.v, t0);
        else                  t1 = vfma2(amp.v, amp.v, t1);
      });
    });
  });

  out[i] = (t0.x + t0.y) + (t1.x + t1.y);
}

// ================= launch =================
extern "C" void kernel_launch(void* const* d_in, const int* in_sizes, int n_in,
                              void* d_out, int out_size, void* d_ws, size_t ws_size,
                              hipStream_t stream) {
  (void)n_in; (void)out_size;
  const int n = in_sizes[0];
  const float*  mBC  = (const float*)d_in[0];
  const float*  mBD  = (const float*)d_in[1];
  const float*  mCD  = (const float*)d_in[2];
  const float*  cBC  = (const float*)d_in[3];
  const float*  cBBC = (const float*)d_in[4];
  const float*  pBC  = (const float*)d_in[5];
  const float*  pBBC = (const float*)d_in[6];
  const float*  cBD  = (const float*)d_in[7];
  const float*  cDBD = (const float*)d_in[8];
  const float*  pDBD = (const float*)d_in[9];
  const float*  cCD  = (const float*)d_in[10];
  const float*  cCCD = (const float*)d_in[11];
  const float*  pCD  = (const float*)d_in[12];
  const float*  pCCD = (const float*)d_in[13];
  const float*  cT1  = (const float*)d_in[14];
  const float*  cT2  = (const float*)d_in[15];
  const float*  p1   = (const float*)d_in[16];
  const float*  p2   = (const float*)d_in[17];
  const float2* parm = (const float2*)d_in[18];

  dim3 block(256);
  dim3 grid((n + 255) / 256);

  if (ws_size >= NH * sizeof(float2)) {
    prep_htab_kernel<<<1, 64, 0, stream>>>(parm, (float2*)d_ws);
    AllAmplitude_59665685676511_kernel<true><<<grid, block, 0, stream>>>(
        mBC, mBD, mCD, cBC, cBBC, pBC, pBBC, cBD, cDBD, pDBD,
        cCD, cCCD, pCD, pCCD, cT1, cT2, p1, p2, parm,
        (const float2*)d_ws, (float*)d_out, n);
  } else {
    AllAmplitude_59665685676511_kernel<false><<<grid, block, 0, stream>>>(
        mBC, mBD, mCD, cBC, cBBC, pBC, pBBC, cBD, cDBD, pDBD,
        cCD, cCCD, pCD, pCCD, cT1, cT2, p1, p2, parm,
        nullptr, (float*)d_out, n);
  }
}

// Round 13
// 46.260 us; speedup vs baseline: 1.2572x; 1.0173x over previous
//
#include <hip/hip_runtime.h>
#include <utility>
#include <type_traits>

typedef float f2 __attribute__((ext_vector_type(2)));

// ================= compile-time math (mirrors reference) =================
constexpr int cabs_i(int x){ return x < 0 ? -x : x; }
constexpr int cmax_i(int a, int b){ return a > b ? a : b; }
constexpr int cmin_i(int a, int b){ return a < b ? a : b; }
constexpr double cfact(int n){ double r = 1.0; for (int i = 2; i <= n; ++i) r *= (double)i; return r; }
constexpr double csqrt_d(double x){
  if (x <= 0.0) return 0.0;
  double r = x > 1.0 ? x : 1.0;
  for (int i = 0; i < 64; ++i) r = 0.5 * (r + x / r);
  return r;
}
constexpr double cg_coef(int j1,int j2,int m1,int m2,int j,int m){
  if (m1 + m2 != m || j < cabs_i(j1 - j2) || j > j1 + j2) return 0.0;
  if (cabs_i(m1) > j1 || cabs_i(m2) > j2 || cabs_i(m) > j) return 0.0;
  double pref = csqrt_d((2.0*j + 1.0) * cfact(j1+j2-j) * cfact(j+j1-j2) * cfact(j+j2-j1) / cfact(j1+j2+j+1));
  pref *= csqrt_d(cfact(j+m)*cfact(j-m)*cfact(j1-m1)*cfact(j1+m1)*cfact(j2-m2)*cfact(j2+m2));
  double s = 0.0;
  const int k0 = cmax_i(0, cmax_i(j2-j-m1, j1+m2-j));
  const int k1 = cmin_i(j1+j2-j, cmin_i(j1-m1, j2+m2));
  for (int k = k0; k <= k1; ++k){
    double t = 1.0/(cfact(k)*cfact(j1+j2-j-k)*cfact(j1-m1-k)*cfact(j2+m2-k)*cfact(j-j2+m1+k)*cfact(j-j1-m2+k));
    s += (k & 1) ? -t : t;
  }
  return pref * s;
}
constexpr double wd_coef(int j,int m1,int m2,int s){
  double pref = csqrt_d(cfact(j+m1)*cfact(j-m1)*cfact(j+m2)*cfact(j-m2));
  double c = pref / (cfact(j+m2-s)*cfact(s)*cfact(m1-m2+s)*cfact(j-m1-s));
  return ((m1-m2+s) & 1) ? -c : c;
}
constexpr double cgetp(double M0,double M1,double M2){
  double s = M1+M2, d = M1-M2;
  double p = (M0-s)*(M0+s)*(M0-d)*(M0+d);
  double pp = 0.5*(p + (p < 0 ? -p : p));
  return csqrt_d(pp)/(2.0*M0);
}

// ================= static_for =================
template<int Start, class F, int... Is>
__device__ inline void static_for_impl(F&& f, std::integer_sequence<int, Is...>){
  (f(std::integral_constant<int, Start + Is>{}), ...);
}
template<int Start, int End, class F>   // [Start, End)
__device__ inline void static_for(F&& f){
  if constexpr (End > Start)
    static_for_impl<Start>(static_cast<F&&>(f), std::make_integer_sequence<int, End - Start>{});
}

// ================= packed complex (re,im in one f2 -> v_pk_* ops) =======
__device__ inline f2 vfma2(f2 a, f2 b, f2 c){ return __builtin_elementwise_fma(a, b, c); }

struct cplx { f2 v; };   // v.x = re, v.y = im
__device__ inline cplx operator+(cplx a, cplx b){ return { a.v + b.v }; }
__device__ inline cplx operator*(cplx a, cplx b){
  f2 sw  = { -a.v.y, a.v.x };
  f2 bre = {  b.v.x, b.v.x };
  f2 bim = {  b.v.y, b.v.y };
  return { vfma2(a.v, bre, sw * bim) };   // 2 packed ops
}
__device__ inline cplx cconj(cplx a){ return { f2{ a.v.x, -a.v.y } }; }
__device__ inline cplx cscale(cplx x, float r){ return { x.v * f2{r, r} }; }  // 1 pk_mul
__device__ inline void caxpy(cplx& acc, float r, cplx x){   // 1 packed fma
  acc.v = vfma2(f2{r, r}, x.v, acc.v);
}

template<int n> __device__ inline float spow(float x){
  if constexpr (n <= 0) return 1.f;
  else return x * spow<n-1>(x);
}
template<int n> __device__ inline f2 vpow(f2 x){
  if constexpr (n <= 0) return f2{1.f, 1.f};
  else return x * vpow<n-1>(x);
}

// ================= wigner d in (u, v, hp) basis =========================
// u=(1+c)/2=ch^2, v=(1-c)/2=sh^2, hp=sqrt(uv)=ch*sh  (theta in [0,pi] -> hp>=0)
struct angs { float u, v, hp; };
__device__ inline angs mkang1(float c){
  angs A;
  A.u = (1.f + c) * 0.5f;
  A.v = (1.f - c) * 0.5f;
  A.hp = __builtin_amdgcn_sqrtf(A.u * A.v);
  return A;
}
struct angp { f2 u, v, hp; };   // packed over TWO DIFFERENT ANGLES
__device__ inline angp mkang2(f2 c){
  angp A;
  A.u = (c + 1.f) * 0.5f;
  A.v = (1.f - c) * 0.5f;
  f2 p = A.u * A.v;
  A.hp = f2{ __builtin_amdgcn_sqrtf(p.x), __builtin_amdgcn_sqrtf(p.y) };
  return A;
}
template<int j, int m1, int m2>
__device__ inline float wigs(const angs& A){
  constexpr int s0 = cmax_i(0, m2 - m1);
  constexpr int s1 = cmin_i(j - m1, j + m2);
  float out = 0.f;
  static_for<s0, s1 + 1>([&](auto S){
    constexpr int s = decltype(S)::value;
    constexpr float coef = (float)wd_coef(j, m1, m2, s);
    constexpr int P = 2*j + m2 - m1 - 2*s;
    constexpr int Q = m1 - m2 + 2*s;
    float mono;
    if constexpr (P & 1) mono = A.hp * spow<(P-1)/2>(A.u) * spow<(Q-1)/2>(A.v);
    else                 mono = spow<P/2>(A.u) * spow<Q/2>(A.v);
    out = fmaf(coef, mono, out);
  });
  return out;
}
template<int j, int m1, int m2>
__device__ inline f2 wig(const angp& A){
  constexpr int s0 = cmax_i(0, m2 - m1);
  constexpr int s1 = cmin_i(j - m1, j + m2);
  f2 out = {0.f, 0.f};
  static_for<s0, s1 + 1>([&](auto S){
    constexpr int s = decltype(S)::value;
    constexpr float coef = (float)wd_coef(j, m1, m2, s);
    constexpr int P = 2*j + m2 - m1 - 2*s;
    constexpr int Q = m1 - m2 + 2*s;
    f2 mono;
    if constexpr (P & 1) mono = A.hp * vpow<(P-1)/2>(A.u) * vpow<(Q-1)/2>(A.v);
    else                 mono = vpow<P/2>(A.u) * vpow<Q/2>(A.v);
    out = vfma2(f2{coef, coef}, mono, out);
  });
  return out;
}

// ================= static LS layout (from reference _build_layout) =====
struct LS { int l, s; };
template<int E> struct Entry;
template<> struct Entry<0>{ static constexpr int off = 0;  static constexpr int n = 2; static constexpr LS ls[2] = {{0,1},{2,1}}; };
template<> struct Entry<1>{ static constexpr int off = 2;  static constexpr int n = 3; static constexpr LS ls[3] = {{0,1},{2,1},{2,2}}; };
template<> struct Entry<2>{ static constexpr int off = 5;  static constexpr int n = 5; static constexpr LS ls[5] = {{0,1},{2,1},{2,2},{2,3},{4,3}}; };
template<> struct Entry<3>{ static constexpr int off = 10; static constexpr int n = 1; static constexpr LS ls[1] = {{2,1}}; };
template<> struct Entry<4>{ static constexpr int off = 11; static constexpr int n = 3; static constexpr LS ls[3] = {{0,1},{2,1},{2,2}}; };
template<> struct Entry<5>{ static constexpr int off = 14; static constexpr int n = 2; static constexpr LS ls[2] = {{0,1},{2,1}}; };

template<int E,int ja,int jb,int jc,int lb,int lc>
constexpr double hcoef(int idx){
  return cg_coef(jb, jc, lb, -lc, Entry<E>::ls[idx].s, lb - lc)
       * cg_coef(Entry<E>::ls[idx].l, Entry<E>::ls[idx].s, 0, lb - lc, ja, lb - lc);
}
template<int E,int ja,int jb,int jc,int lb,int lc>
constexpr bool hnz(){
  bool any = false;
  for (int i = 0; i < Entry<E>::n; ++i) if (hcoef<E,ja,jb,jc,lb,lc>(i) != 0.0) any = true;
  return any;
}
template<int E,int ja,int jb,int jc,int lb,int lc>
__device__ inline cplx H_ls(const cplx* par){
  cplx tot{ f2{0.f, 0.f} };
  static_for<0, Entry<E>::n>([&](auto I){
    constexpr double c = hcoef<E,ja,jb,jc,lb,lc>(decltype(I)::value);
    if constexpr (c != 0.0){
      caxpy(tot, (float)c, par[Entry<E>::off + decltype(I)::value]);
    }
  });
  return tot;
}

// ================= H table layout in d_ws =================
constexpr int IH10(int lDB){ return lDB+1; }                       // 0..2
constexpr int IH20(int lD,int lB){ return 3+(lD+1)*3+(lB+1); }     // 3..11
constexpr int IH11(int lBC,int lD){ return 12+(lBC+2)*3+(lD+1); }  // 12..26
constexpr int IH21(int lB2){ return 27+(lB2+1)/2; }                // 27..28
constexpr int IH12(int lCD,int lB){ return 29+(lCD+1)*3+(lB+1); }  // 29..37
constexpr int IH22(int lC2){ return 38+(lC2+1); }                  // 38..40
constexpr int NH = 41;

__device__ inline void compute_htab(const float2* __restrict__ g_par, cplx* t){
  cplx par[16];
  #pragma unroll
  for (int k = 0; k < 16; ++k){ float2 p = g_par[k]; par[k].v = f2{p.x, p.y}; }
  static_for<-1,2>([&](auto L){ constexpr int l = decltype(L)::value; t[IH10(l)] = H_ls<0,1,1,0,l,0>(par); });
  static_for<-1,2>([&](auto D){ constexpr int lD = decltype(D)::value;
    static_for<-1,2>([&](auto B){ constexpr int lB = decltype(B)::value;
      t[IH20(lD,lB)] = H_ls<1,1,1,1,lD,lB>(par); }); });
  static_for<-2,3>([&](auto C){ constexpr int lBC = decltype(C)::value;
    static_for<-1,2>([&](auto D){ constexpr int lD = decltype(D)::value;
      t[IH11(lBC,lD)] = H_ls<2,1,2,1,lBC,lD>(par); }); });
  t[IH21(-1)] = H_ls<3,2,1,0,-1,0>(par);
  t[IH21( 1)] = H_ls<3,2,1,0, 1,0>(par);
  static_for<-1,2>([&](auto C){ constexpr int lCD = decltype(C)::value;
    static_for<-1,2>([&](auto B){ constexpr int lB = decltype(B)::value;
      t[IH12(lCD,lB)] = H_ls<4,1,1,1,lCD,lB>(par); }); });
  static_for<-1,2>([&](auto C){ constexpr int lC2 = decltype(C)::value;
    t[IH22(lC2)] = H_ls<5,1,0,1,0,lC2>(par); });
}

template<int IDX, bool PRE>
__device__ inline cplx getH(const float2* __restrict__ hs, const cplx* ht){
  if constexpr (PRE){ float2 v = hs[IDX]; return cplx{ f2{v.x, v.y} }; }
  else return ht[IDX];
}
#define GH(IDX) getH<(IDX), PRE>(hs, ht)

// ================= physics constants =================
constexpr double dM0B = 2.01026, dM0C = 0.13957061, dM0D = 2.00685;
constexpr double dR0m0 = 4.026,  dR0g0 = 0.025;    // BD chain, J=1
constexpr double dR1m0 = 2.4607, dR1g0 = 0.0475;   // BC chain, J=2
constexpr double dR2m0 = 2.4232, dR2g0 = 0.025;    // CD chain, J=1

constexpr float M0SQ0 = (float)(dR0m0*dR0m0);
constexpr float M0SQ1 = (float)(dR1m0*dR1m0);
constexpr float M0SQ2 = (float)(dR2m0*dR2m0);
constexpr float S2_0 = (float)((dM0B+dM0D)*(dM0B+dM0D)), D2_0 = (float)((dM0B-dM0D)*(dM0B-dM0D));
constexpr float S2_1 = (float)((dM0B+dM0C)*(dM0B+dM0C)), D2_1 = (float)((dM0B-dM0C)*(dM0B-dM0C));
constexpr float S2_2 = (float)((dM0C+dM0D)*(dM0C+dM0D)), D2_2 = (float)((dM0C-dM0D)*(dM0C-dM0D));
constexpr float K0 = (float)(2.0 * cgetp(dR0m0, dM0B, dM0D) / (dR0g0 * dR0m0 * dR0m0));
constexpr float K1 = (float)(2.0 * cgetp(dR1m0, dM0B, dM0C) / (dR1g0 * dR1m0 * dR1m0));
constexpr float K2 = (float)(2.0 * cgetp(dR2m0, dM0C, dM0D) / (dR2g0 * dR2m0 * dR2m0));

__device__ inline void bw_eval2(f2 m, f2 K, f2 m0sq, f2 S2, f2 D2, cplx& o0, cplx& o1){
  f2 m2 = m * m;
  f2 t  = m0sq - m2;
  f2 p  = (m2 - S2) * (m2 - D2);
  f2 pp = f2{ fmaxf(p.x, 0.f), fmaxf(p.y, 0.f) };
  f2 rs = f2{ __builtin_amdgcn_rsqf(pp.x), __builtin_amdgcn_rsqf(pp.y) };
  f2 r  = K * t * m2 * rs;
  float i0 = __builtin_amdgcn_rcpf(fmaf(r.x, r.x, 1.f));
  float i1 = __builtin_amdgcn_rcpf(fmaf(r.y, r.y, 1.f));
  o0 = { f2{ r.x * i0, i0 } };
  o1 = { f2{ r.y * i1, i1 } };
}
__device__ inline cplx bw_eval(float m, float K, float m0sq, float S2, float D2){
  float m2 = m * m;
  float t  = m0sq - m2;
  float p  = (m2 - S2) * (m2 - D2);
  float pp = fmaxf(p, 0.f);
  float r  = K * t * m2 * __builtin_amdgcn_rsqf(pp);
  float inv = __builtin_amdgcn_rcpf(fmaf(r, r, 1.f));
  return { f2{ r * inv, inv } };
}
__device__ inline cplx phase_neg(float phi){  // exp(-i*phi)
  return { f2{ __cosf(phi), -__sinf(phi) } };
}

// ================= pre-kernel: uniform H couplings -> d_ws =================
__global__ void prep_htab_kernel(const float2* __restrict__ g_par, float2* __restrict__ ws){
  if (blockIdx.x != 0 || threadIdx.x != 0) return;
  cplx t[NH];
  compute_htab(g_par, t);
  #pragma unroll
  for (int k = 0; k < NH; ++k) ws[k] = make_float2(t[k].v.x, t[k].v.y);
}

// ================= main kernel (64-thread workgroups) =================
template<bool PRE>
__global__ void __launch_bounds__(64)
AllAmplitude_59665685676511_kernel(
    const float* __restrict__ g_mBC,  const float* __restrict__ g_mBD,  const float* __restrict__ g_mCD,
    const float* __restrict__ g_cBC,  const float* __restrict__ g_cBBC, const float* __restrict__ g_pBC,  const float* __restrict__ g_pBBC,
    const float* __restrict__ g_cBD,  const float* __restrict__ g_cDBD, const float* __restrict__ g_pDBD,
    const float* __restrict__ g_cCD,  const float* __restrict__ g_cCCD, const float* __restrict__ g_pCD,  const float* __restrict__ g_pCCD,
    const float* __restrict__ g_cT1,  const float* __restrict__ g_cT2,  const float* __restrict__ g_p1,   const float* __restrict__ g_p2,
    const float2* __restrict__ g_par, const float2* __restrict__ hs,
    float* __restrict__ out, int n)
{
  int i = blockIdx.x * 64 + threadIdx.x;
  if (i >= n) return;

  cplx ht[NH];
  if constexpr (!PRE) compute_htab(g_par, ht);

  // ---------- angles (u,v,hp); packed pairs over DIFFERENT angles ----------
  angp PBDT1  = mkang2(f2{ g_cBD[i], g_cT1[i]  });   // (BD, T1)
  angp PT2CCD = mkang2(f2{ g_cT2[i], g_cCCD[i] });   // (T2, CCD)
  angp PBCCD  = mkang2(f2{ g_cBC[i], g_cCD[i]  });   // (BC, CD)
  angs SDBD   = mkang1(g_cDBD[i]);
  angs SBBC   = mkang1(g_cBBC[i]);

  // ---------- wigner tables ----------
  f2 dBDT1[2][3];
  static_for<0,2>([&](auto R_){ constexpr int r = decltype(R_)::value; constexpr int m1 = 2*r-1;
    static_for<-1,2>([&](auto M_){ constexpr int m2 = decltype(M_)::value;
      dBDT1[r][m2+1] = wig<1, m1, m2>(PBDT1); }); });
  f2 dT2CCD[3][3];
  static_for<-1,2>([&](auto M1_){ constexpr int m1 = decltype(M1_)::value;
    static_for<-1,2>([&](auto M2_){ constexpr int m2 = decltype(M2_)::value;
      dT2CCD[m1+1][m2+1] = wig<1, m1, m2>(PT2CCD); }); });
  f2 dBCCD[2][3];
  static_for<0,2>([&](auto A_){ constexpr int a = decltype(A_)::value; constexpr int lA = 2*a-1;
    static_for<-1,2>([&](auto M_){ constexpr int dm = decltype(M_)::value;
      dBCCD[a][dm+1] = wig<1, lA, dm>(PBCCD); }); });
  float dDBD[3][3], dBBC[5][2];
  static_for<-1,2>([&](auto M1_){ constexpr int m1 = decltype(M1_)::value;
    static_for<-1,2>([&](auto M2_){ constexpr int m2 = decltype(M2_)::value;
      dDBD[m1+1][m2+1] = wigs<1, m1, m2>(SDBD); }); });
  static_for<-2,3>([&](auto C_){ constexpr int lBC = decltype(C_)::value;
    static_for<0,2>([&](auto K_){ constexpr int k = decltype(K_)::value; constexpr int lB2 = 2*k-1;
      dBBC[lBC+2][k] = wigs<2, lBC, lB2>(SBBC); }); });

  // ---------- Breit-Wigners ----------
  cplx bw0, bw1;
  bw_eval2(f2{ g_mBD[i], g_mBC[i] }, f2{K0, K1}, f2{M0SQ0, M0SQ1},
           f2{S2_0, S2_1}, f2{D2_0, D2_1}, bw0, bw1);
  const cplx bw2 = bw_eval(g_mCD[i], K2, M0SQ2, S2_2, D2_2);

  // ---------- res1: HT1 then rank-2 contraction into Am/Ap ----------
  cplx Am[2][3], Ap[2][3];
  {
    cplx HT1[5][3] = {};   // [lBC+2][lD+1] : H1_1 * e_BC^lBC * bw1
    {
      const cplx eBC = phase_neg(g_pBC[i]);
      const cplx e2  = eBC * eBC;
      cplx T1B[5] = { cconj(e2) * bw1, cconj(eBC) * bw1, bw1, eBC * bw1, e2 * bw1 };
      static_for<-2,3>([&](auto C_){ constexpr int lBC = decltype(C_)::value;
        static_for<-1,2>([&](auto D_){ constexpr int lD = decltype(D_)::value;
          if constexpr (cabs_i(lBC - lD) <= 1 && hnz<2,1,2,1,lBC,lD>())
            HT1[lBC+2][lD+1] = GH(IH11(lBC,lD)) * T1B[lBC+2];
        }); });
    }
    cplx eP1 = phase_neg(g_p1[i] + g_pBBC[i]);
    cplx U1m = GH(IH21(-1)) * cconj(eP1);
    cplx U1p = GH(IH21( 1)) * eP1;
    cplx Qm[5], Qp[5];
    static_for<-2,3>([&](auto C_){ constexpr int lBC = decltype(C_)::value;
      Qm[lBC+2] = cscale(U1m, dBBC[lBC+2][0]);
      Qp[lBC+2] = cscale(U1p, dBBC[lBC+2][1]); });
    cplx Tm[5][3], Tp[5][3];
    static_for<-2,3>([&](auto C_){ constexpr int lBC = decltype(C_)::value;
      static_for<-1,2>([&](auto D_){ constexpr int lD = decltype(D_)::value;
        if constexpr (cabs_i(lBC - lD) <= 1 && hnz<2,1,2,1,lBC,lD>()){
          Tm[lBC+2][lD+1] = HT1[lBC+2][lD+1] * Qm[lBC+2];
          Tp[lBC+2][lD+1] = HT1[lBC+2][lD+1] * Qp[lBC+2];
        }
      }); });
    static_for<0,2>([&](auto A_){ constexpr int a = decltype(A_)::value;
      static_for<-1,2>([&](auto D_){ constexpr int lD = decltype(D_)::value;
        cplx am{ f2{0.f,0.f} }, ap{ f2{0.f,0.f} };
        static_for<-1,2>([&](auto M_){ constexpr int dm = decltype(M_)::value; constexpr int lBC = lD + dm;
          if constexpr (hnz<2,1,2,1,lBC,lD>()){
            caxpy(am, dBCCD[a][dm+1].x, Tm[lBC+2][lD+1]);
            caxpy(ap, dBCCD[a][dm+1].x, Tp[lBC+2][lD+1]);
          }
        });
        Am[a][lD+1] = am;
        Ap[a][lD+1] = ap;
      }); });
  }

  // ---------- res0 spine: G0[a][(lD-lB)+1] (pre-scaled: P0 = dDBD*H10) ----------
  cplx G0[2][3];
  {
    cplx P0[3][3];
    static_for<-1,2>([&](auto L_){ constexpr int lDB = decltype(L_)::value;
      cplx h = GH(IH10(lDB));
      static_for<0,3>([&](auto M_){ constexpr int mi = decltype(M_)::value;
        P0[lDB+1][mi] = cscale(h, dDBD[lDB+1][mi]); }); });
    static_for<0,2>([&](auto A_){ constexpr int a = decltype(A_)::value;
      static_for<0,3>([&](auto M_){ constexpr int mi = decltype(M_)::value;
        cplx acc{ f2{0.f, 0.f} };
        static_for<-1,2>([&](auto L_){ constexpr int lDB = decltype(L_)::value;
          caxpy(acc, dBDT1[a][lDB+1].x, P0[lDB+1][mi]);
        });
        G0[a][mi] = acc; }); });
  }

  // ---------- res2 spine: V2[lD+1][lCD+1] (pre-scaled: R2t = dCCD*U2) ----------
  cplx V2[3][3];
  {
    cplx eP2 = phase_neg(g_p2[i] + g_pCCD[i]);
    cplx U2[3];
    U2[0] = GH(IH22(-1)) * cconj(eP2);
    U2[1] = GH(IH22(0));
    U2[2] = GH(IH22(1)) * eP2;
    cplx R2t[3][3];
    static_for<-1,2>([&](auto C_){ constexpr int lCD = decltype(C_)::value;
      static_for<-1,2>([&](auto X_){ constexpr int lC2 = decltype(X_)::value;
        R2t[lCD+1][lC2+1] = cscale(U2[lC2+1], dT2CCD[lCD+1][lC2+1].y); }); });
    static_for<-1,2>([&](auto D_){ constexpr int lD = decltype(D_)::value;
      static_for<-1,2>([&](auto C_){ constexpr int lCD = decltype(C_)::value;
        cplx acc{ f2{0.f, 0.f} };
        static_for<-1,2>([&](auto X_){ constexpr int lC2 = decltype(X_)::value;
          caxpy(acc, dT2CCD[lC2+1][lD+1].x, R2t[lCD+1][lC2+1]);
        });
        V2[lD+1][lCD+1] = acc; }); });
  }

  // ---------- remaining coupling tables ----------
  cplx W0T[3][3] = {};   // [lD+1][lB+1] : H2_0 * e_D^lD * bw0
  {
    const cplx eD = phase_neg(g_pDBD[i]);
    cplx EBW0[3] = { cconj(eD) * bw0, bw0, eD * bw0 };
    static_for<-1,2>([&](auto D_){ constexpr int lD = decltype(D_)::value;
      static_for<-1,2>([&](auto B_){ constexpr int lB = decltype(B_)::value;
        if constexpr (cabs_i(lD - lB) <= 1 && hnz<1,1,1,1,lD,lB>())
          W0T[lD+1][lB+1] = GH(IH20(lD,lB)) * EBW0[lD+1];
      }); });
  }
  cplx HT2[3][3] = {};   // [lCD+1][lB+1] : H1_2 * e_CD^lCD * bw2
  {
    const cplx eCD = phase_neg(g_pCD[i]);
    cplx T2B[3] = { cconj(eCD) * bw2, bw2, eCD * bw2 };
    static_for<-1,2>([&](auto C_){ constexpr int lCD = decltype(C_)::value;
      static_for<-1,2>([&](auto B_){ constexpr int lB = decltype(B_)::value;
        if constexpr (cabs_i(lCD - lB) <= 1 && hnz<4,1,1,1,lCD,lB>())
          HT2[lCD+1][lB+1] = GH(IH12(lCD,lB)) * T2B[lCD+1];
      }); });
  }

  // ---------- 18-combo helicity sum ----------
  f2 t0 = {0.f, 0.f}, t1 = {0.f, 0.f};
  static_for<-1,2>([&](auto B_){ constexpr int lB = decltype(B_)::value;
    const float dT1m = dBDT1[0][lB+1].y;
    const float dT1p = dBDT1[1][lB+1].y;
    static_for<-1,2>([&](auto D_){ constexpr int lD = decltype(D_)::value;
      cplx Y2[3] = {};
      static_for<-1,2>([&](auto M_){ constexpr int dm = decltype(M_)::value; constexpr int lCD = lB + dm;
        if constexpr (cabs_i(lCD) <= 1 && hnz<4,1,1,1,lCD,lB>())
          Y2[dm+1] = HT2[lCD+1][lB+1] * V2[lD+1][lCD+1];
      });
      static_for<0,2>([&](auto A_){ constexpr int a = decltype(A_)::value;
        cplx amp{ f2{0.f, 0.f} };
        if constexpr (cabs_i(lD - lB) <= 1 && hnz<1,1,1,1,lD,lB>())
          amp = W0T[lD+1][lB+1] * G0[a][lD-lB+1];
        // res1 (rank-2 factor)
        caxpy(amp, dT1m, Am[a][lD+1]);
        caxpy(amp, dT1p, Ap[a][lD+1]);
        // res2
        static_for<-1,2>([&](auto M_){ constexpr int dm = decltype(M_)::value; constexpr int lCD = lB + dm;
          if constexpr (cabs_i(lCD) <= 1 && hnz<4,1,1,1,lCD,lB>())
            caxpy(amp, dBCCD[a][dm+1].y, Y2[dm+1]);
        });
        if constexpr (a == 0) t0 = vfma2(amp.v, amp.v, t0);
        else                  t1 = vfma2(amp.v, amp.v, t1);
      });
    });
  });

  out[i] = (t0.x + t0.y) + (t1.x + t1.y);
}

// ================= launch =================
extern "C" void kernel_launch(void* const* d_in, const int* in_sizes, int n_in,
                              void* d_out, int out_size, void* d_ws, size_t ws_size,
                              hipStream_t stream) {
  (void)n_in; (void)out_size;
  const int n = in_sizes[0];
  const float*  mBC  = (const float*)d_in[0];
  const float*  mBD  = (const float*)d_in[1];
  const float*  mCD  = (const float*)d_in[2];
  const float*  cBC  = (const float*)d_in[3];
  const float*  cBBC = (const float*)d_in[4];
  const float*  pBC  = (const float*)d_in[5];
  const float*  pBBC = (const float*)d_in[6];
  const float*  cBD  = (const float*)d_in[7];
  const float*  cDBD = (const float*)d_in[8];
  const float*  pDBD = (const float*)d_in[9];
  const float*  cCD  = (const float*)d_in[10];
  const float*  cCCD = (const float*)d_in[11];
  const float*  pCD  = (const float*)d_in[12];
  const float*  pCCD = (const float*)d_in[13];
  const float*  cT1  = (const float*)d_in[14];
  const float*  cT2  = (const float*)d_in[15];
  const float*  p1   = (const float*)d_in[16];
  const float*  p2   = (const float*)d_in[17];
  const float2* parm = (const float2*)d_in[18];

  dim3 block(64);
  dim3 grid((n + 63) / 64);

  if (ws_size >= NH * sizeof(float2)) {
    prep_htab_kernel<<<1, 64, 0, stream>>>(parm, (float2*)d_ws);
    AllAmplitude_59665685676511_kernel<true><<<grid, block, 0, stream>>>(
        mBC, mBD, mCD, cBC, cBBC, pBC, pBBC, cBD, cDBD, pDBD,
        cCD, cCCD, pCD, pCCD, cT1, cT2, p1, p2, parm,
        (const float2*)d_ws, (float*)d_out, n);
  } else {
    AllAmplitude_59665685676511_kernel<false><<<grid, block, 0, stream>>>(
        mBC, mBD, mCD, cBC, cBBC, pBC, pBBC, cBD, cDBD, pDBD,
        cCD, cCCD, pCD, pCCD, cT1, cT2, p1, p2, parm,
        nullptr, (float*)d_out, n);
  }
}